// Round 4
// baseline (126.912 us; speedup 1.0000x reference)
//
#include <hip/hip_runtime.h>

#define IMG_H 1080
#define IMG_W 1920
#define NBATCH 8
#define LSTRIP 15            // output rows per lane
#define BROWS (4*LSTRIP)     // 60 rows per block (4 wave-uniform strips)
#define NK (LSTRIP+4)        // schedule iterations (19)

// Wave-uniform-row, LDS-free fused Shi-Tomasi.
// lane = 4 cols x 15 rows; block = 64 col-groups (256 cols) x 4 strips (60 rows).
// strip = tid>>6 -> s0 / row clamps / top-bottom fixes are wave-uniform =>
// scalar pipe + s_cbranch (no per-lane clamp/cndmask). Loads: 3x 16B aligned
// from wb = vb-4. Edge column handling compiled only into blockIdx.x 0/7.
// 5-deep raw ring, prefetch distance 4. Double-clamp semantics as validated
// in R2/R3: row fix via h-ring copy at vr==-1 / vr==H; col fix via hfd/hfs.

template<bool EDGE>
__device__ __forceinline__ void st_body(const float* __restrict__ g,
                                        float* __restrict__ orow,
                                        int vb, int s0) {
    const bool eL = EDGE && (vb == 0);
    const bool eR = EDGE && (vb == IMG_W - 4);
    int wb = vb - 4;
    if (EDGE) { if (eL) wb = 0; if (eR) wb = IMG_W - 12; }   // stay in-bounds
    const bool topFix = (s0 == 0);                 // wave-uniform
    const bool botFix = (s0 + LSTRIP == IMG_H);    // wave-uniform

    float raw[5][12];
    float hdR[3][6], hsR[3][6], hfd[3], hfs[3], h[3][12];

    auto issue = [&](int k) {
        int lr = s0 - 2 + k;                       // wave-uniform -> scalar
        lr = max(0, min(IMG_H - 1, lr));
        const float4* rp = (const float4*)(g + (size_t)lr * IMG_W + wb);
        const float4 a = rp[0], b2 = rp[1], c = rp[2];
        float* r = raw[k % 5];
        r[0]=a.x;  r[1]=a.y;  r[2]=a.z;  r[3]=a.w;
        r[4]=b2.x; r[5]=b2.y; r[6]=b2.z; r[7]=b2.w;
        r[8]=c.x;  r[9]=c.y;  r[10]=c.z; r[11]=c.w;
    };

    #pragma unroll
    for (int k = 0; k < 4; ++k) issue(k);          // preload s0-2 .. s0+1

    #pragma unroll
    for (int k = 0; k < NK; ++k) {                 // schedule row sr = s0-2+k
        if (k + 4 < NK) issue(k + 4);              // prefetch distance 4

        // ---- separable partials for schedule row k ----
        {
            const float* r = raw[k % 5];
            float z[8];                            // virtual cols vb-2..vb+5
            if (EDGE) {
                const float zL[8] = {r[0],r[0],r[0],r[1],r[2],r[3],r[4],r[5]};
                const float zR[8] = {r[6],r[7],r[8],r[9],r[10],r[11],r[11],r[11]};
                #pragma unroll
                for (int j = 0; j < 8; ++j)
                    z[j] = eL ? zL[j] : (eR ? zR[j] : r[j + 2]);
                // double-clamped edge column partials (virtual col -1 / W)
                hfd[k % 3] = eR ? (z[5] - z[4]) : (z[3] - z[2]);
                hfs[k % 3] = eR ? (z[4] + 3.0f * z[5]) : (3.0f * z[2] + z[3]);
            } else {
                #pragma unroll
                for (int j = 0; j < 8; ++j) z[j] = r[j + 2];
            }
            float* hd = hdR[k % 3];
            float* hs = hsR[k % 3];
            #pragma unroll
            for (int t = 0; t < 6; ++t) {
                hd[t] = z[t + 2] - z[t];
                hs[t] = fmaf(2.0f, z[t + 1], z[t]) + z[t + 2];
            }
        }

        // ---- product row vr = s0-3+k (k>=2) ----
        if (k >= 2) {
            const int rr = k - 2;
            const int sm = rr % 3, sz = (rr + 1) % 3, sp = (rr + 2) % 3;

            float Ix[6], Iy[6];
            #pragma unroll
            for (int t = 0; t < 6; ++t) {
                Ix[t] = hdR[sm][t] + 2.0f * hdR[sz][t] + hdR[sp][t];
                Iy[t] = hsR[sp][t] - hsR[sm][t];
            }
            if (EDGE) {
                const float ixf = hfd[sm] + 2.0f * hfd[sz] + hfd[sp];
                const float iyf = hfs[sp] - hfs[sm];
                if (eL) { Ix[0] = ixf; Iy[0] = iyf; }
                if (eR) { Ix[5] = ixf; Iy[5] = iyf; }
            }

            float pxx[6], pyy[6], pxy[6];
            #pragma unroll
            for (int t = 0; t < 6; ++t) {
                pxx[t] = Ix[t] * Ix[t];
                pyy[t] = Iy[t] * Iy[t];
                pxy[t] = Ix[t] * Iy[t];
            }
            float* hr = h[rr % 3];
            #pragma unroll
            for (int o = 0; o < 4; ++o) {
                hr[o]     = pxx[o] + pxx[o+1] + pxx[o+2];
                hr[4 + o] = pyy[o] + pyy[o+1] + pyy[o+2];
                hr[8 + o] = pxy[o] + pxy[o+1] + pxy[o+2];
            }
            // top: P(vr=-1) == P(vr=0)  (wave-uniform scalar branch)
            if (rr == 1 && topFix) {
                #pragma unroll
                for (int q = 0; q < 12; ++q) h[0][q] = hr[q];
            }
            // bottom: P(vr=H) == P(vr=H-1)
            if (rr == LSTRIP + 1 && botFix) {
                const float* hprev = h[(rr - 1) % 3];
                #pragma unroll
                for (int q = 0; q < 12; ++q) hr[q] = hprev[q];
            }

            if (rr >= 2) {
                const float* h0 = h[(rr - 2) % 3];
                const float* h1 = h[(rr - 1) % 3];
                const float* h2 = hr;
                float rv[4];
                #pragma unroll
                for (int o = 0; o < 4; ++o) {
                    const float sxx = h0[o]     + h1[o]     + h2[o];
                    const float syy = h0[4 + o] + h1[4 + o] + h2[4 + o];
                    const float sxy = h0[8 + o] + h1[8 + o] + h2[8 + o];
                    const float ht   = 0.5f * (sxx + syy);
                    const float dh   = 0.5f * (sxx - syy);
                    const float disc = fmaf(dh, dh, fmaf(sxy, sxy, 1e-10f));
                    rv[o] = fmaxf(ht - sqrtf(disc), 0.0f);
                }
                *(float4*)orow = make_float4(rv[0], rv[1], rv[2], rv[3]);
                orow += IMG_W;
            }
        }
    }
}

__global__ __launch_bounds__(256, 3)
void shi_tomasi_kernel(const float* __restrict__ img, float* __restrict__ out) {
    const int cg    = threadIdx.x & 63;            // 64 col-groups x 4 cols
    const int strip = threadIdx.x >> 6;            // wave-uniform strip 0..3
    const int vb = blockIdx.x * 256 + cg * 4;
    if (vb >= IMG_W) return;                       // masked half of block x=7
    const int s0 = blockIdx.y * BROWS + strip * LSTRIP;
    const float* g = img + (size_t)blockIdx.z * (IMG_H * IMG_W);
    float* orow = out + ((size_t)blockIdx.z * IMG_H + s0) * IMG_W + vb;

    if (blockIdx.x == 0 || blockIdx.x == gridDim.x - 1)
        st_body<true>(g, orow, vb, s0);
    else
        st_body<false>(g, orow, vb, s0);
}

extern "C" void kernel_launch(void* const* d_in, const int* in_sizes, int n_in,
                              void* d_out, int out_size, void* d_ws, size_t ws_size,
                              hipStream_t stream) {
    const float* img = (const float*)d_in[0];
    float* out = (float*)d_out;
    dim3 grid(8, IMG_H / BROWS, NBATCH);           // 8 x 18 x 8 = 1152 blocks
    shi_tomasi_kernel<<<grid, 256, 0, stream>>>(img, out);
}

// Round 5
// 121.901 us; speedup vs baseline: 1.0411x; 1.0411x over previous
//
#include <hip/hip_runtime.h>

typedef float v2f __attribute__((ext_vector_type(2)));
typedef float v4f __attribute__((ext_vector_type(4)));

#define IMG_H 1080
#define IMG_W 1920
#define NBATCH 8
#define LSTRIP 9             // output rows per lane
#define BROWS (4*LSTRIP)     // 36 rows per block (4 wave-uniform strips)
#define NK (LSTRIP+4)        // 13 schedule iterations

// Packed-fp32 (v_pk_*) fused Shi-Tomasi. lane = 4 cols x 9 rows;
// block = 64 col-groups (256 cols) x 4 wave-uniform strips; grid 8x30x8 =
// 1920 blocks (restores R3's winning TLP). All column-wise math expressed on
// float2 ext-vectors so ISel emits v_pk_add/mul/fma_f32 (gfx950 full-rate
// packed fp32) -- targets the stubborn ~22us VALU-busy floor of R2-R4.
// Ring: 4 raw rows, prefetch distance 3. Edge algebra identical to the
// validated R2-R4 double-clamp scheme.

static __device__ __forceinline__ v2f vfma2(v2f a, v2f b, v2f c) {
    return __builtin_elementwise_fma(a, b, c);
}

template<bool EDGE>
__device__ __forceinline__ void st_body(const float* __restrict__ g,
                                        float* __restrict__ outb,
                                        int vb, int s0) {
    const bool eL = EDGE && (vb == 0);
    const bool eR = EDGE && (vb == IMG_W - 4);
    int wb = vb - 4;
    if (EDGE) { if (eL) wb = 0; if (eR) wb = IMG_W - 12; }
    const bool topFix = (s0 == 0);                 // wave-uniform
    const bool botFix = (s0 + LSTRIP == IMG_H);    // wave-uniform

    v2f R[4][6];                 // raw ring (pairs), slot = k%4
    v2f hdR[3][3], hsR[3][3];    // separable partial rings (3 pairs wide)
    float hfd[3], hfs[3];        // double-clamped edge-col partials
    v2f hxx[3][2], hyy[3][2], hxy[3][2];   // horizontal box-sum rings

    auto issue = [&](int k) {
        int lr = s0 - 2 + k;                       // wave-uniform -> scalar
        lr = max(0, min(IMG_H - 1, lr));
        const float4* rp = (const float4*)(g + (size_t)lr * IMG_W + wb);
        const float4 A = rp[0], B = rp[1], C = rp[2];
        v2f* r = R[k % 4];
        r[0] = v2f{A.x, A.y}; r[1] = v2f{A.z, A.w};
        r[2] = v2f{B.x, B.y}; r[3] = v2f{B.z, B.w};
        r[4] = v2f{C.x, C.y}; r[5] = v2f{C.z, C.w};
    };

    issue(0); issue(1); issue(2);          // preload s0-2 .. s0

    const v2f two = {2.0f, 2.0f};

    #pragma unroll
    for (int k = 0; k < NK; ++k) {         // schedule row sr = s0-2+k
        if (k + 3 < NK) issue(k + 3);      // prefetch distance 3

        // ---- separable partials for schedule row k ----
        {
            const v2f* r = R[k % 4];
            v2f Za, Zb, Zc, Zd, Sab, Sbc, Scd;
            if (EDGE) {
                const float rs[12] = {r[0].x, r[0].y, r[1].x, r[1].y,
                                      r[2].x, r[2].y, r[3].x, r[3].y,
                                      r[4].x, r[4].y, r[5].x, r[5].y};
                const float zL[8] = {rs[0],rs[0],rs[0],rs[1],rs[2],rs[3],rs[4],rs[5]};
                const float zR[8] = {rs[6],rs[7],rs[8],rs[9],rs[10],rs[11],rs[11],rs[11]};
                float z[8];
                #pragma unroll
                for (int j = 0; j < 8; ++j)
                    z[j] = eL ? zL[j] : (eR ? zR[j] : rs[j + 2]);
                hfd[k % 3] = eR ? (z[5] - z[4]) : (z[3] - z[2]);
                hfs[k % 3] = eR ? (z[4] + 3.0f * z[5]) : (3.0f * z[2] + z[3]);
                Za = v2f{z[0], z[1]}; Zb = v2f{z[2], z[3]};
                Zc = v2f{z[4], z[5]}; Zd = v2f{z[6], z[7]};
                Sab = v2f{z[1], z[2]}; Sbc = v2f{z[3], z[4]}; Scd = v2f{z[5], z[6]};
            } else {
                Za = r[1]; Zb = r[2]; Zc = r[3]; Zd = r[4];
                Sab = v2f{r[1].y, r[2].x};
                Sbc = v2f{r[2].y, r[3].x};
                Scd = v2f{r[3].y, r[4].x};
            }
            v2f* hd = hdR[k % 3];
            v2f* hs = hsR[k % 3];
            hd[0] = Zb - Za; hd[1] = Zc - Zb; hd[2] = Zd - Zc;
            hs[0] = vfma2(Sab, two, Za) + Zb;
            hs[1] = vfma2(Sbc, two, Zb) + Zc;
            hs[2] = vfma2(Scd, two, Zc) + Zd;
        }

        // ---- product row vr = s0-1+(k-2) (k>=2) ----
        if (k >= 2) {
            const int rr = k - 2;
            const int sm = rr % 3, sz = (rr + 1) % 3, sp = (rr + 2) % 3;

            v2f Ixp[3], Iyp[3];
            #pragma unroll
            for (int j = 0; j < 3; ++j) {
                Ixp[j] = vfma2(hdR[sz][j], two, hdR[sm][j]) + hdR[sp][j];
                Iyp[j] = hsR[sp][j] - hsR[sm][j];
            }
            if (EDGE) {
                const float ixf = hfd[sm] + 2.0f * hfd[sz] + hfd[sp];
                const float iyf = hfs[sp] - hfs[sm];
                if (eL) { Ixp[0].x = ixf; Iyp[0].x = iyf; }
                if (eR) { Ixp[2].y = ixf; Iyp[2].y = iyf; }
            }

            v2f xx[3], yy[3], xy[3];
            #pragma unroll
            for (int j = 0; j < 3; ++j) {
                xx[j] = Ixp[j] * Ixp[j];
                yy[j] = Iyp[j] * Iyp[j];
                xy[j] = Ixp[j] * Iyp[j];
            }
            // horizontal 3-sums: pairs (s0,s1), (s2,s3) per matrix
            {
                v2f* hx = hxx[rr % 3];
                v2f* hy = hyy[rr % 3];
                v2f* hz = hxy[rr % 3];
                hx[0] = xx[0] + v2f{xx[0].y, xx[1].x} + xx[1];
                hx[1] = xx[1] + v2f{xx[1].y, xx[2].x} + xx[2];
                hy[0] = yy[0] + v2f{yy[0].y, yy[1].x} + yy[1];
                hy[1] = yy[1] + v2f{yy[1].y, yy[2].x} + yy[2];
                hz[0] = xy[0] + v2f{xy[0].y, xy[1].x} + xy[1];
                hz[1] = xy[1] + v2f{xy[1].y, xy[2].x} + xy[2];
            }
            // top: P(vr=-1) == P(vr=0)  (wave-uniform branch)
            if (rr == 1 && topFix) {
                #pragma unroll
                for (int q = 0; q < 2; ++q) {
                    hxx[0][q] = hxx[1][q]; hyy[0][q] = hyy[1][q]; hxy[0][q] = hxy[1][q];
                }
            }
            // bottom: P(vr=H) == P(vr=H-1)
            if (rr == LSTRIP + 1 && botFix) {
                #pragma unroll
                for (int q = 0; q < 2; ++q) {
                    hxx[rr % 3][q] = hxx[(rr - 1) % 3][q];
                    hyy[rr % 3][q] = hyy[(rr - 1) % 3][q];
                    hxy[rr % 3][q] = hxy[(rr - 1) % 3][q];
                }
            }

            if (rr >= 2) {
                const int a = (rr - 2) % 3, b2 = (rr - 1) % 3, c = rr % 3;
                float rv[4];
                #pragma unroll
                for (int q = 0; q < 2; ++q) {
                    const v2f sxx = hxx[a][q] + hxx[b2][q] + hxx[c][q];
                    const v2f syy = hyy[a][q] + hyy[b2][q] + hyy[c][q];
                    const v2f sxy = hxy[a][q] + hxy[b2][q] + hxy[c][q];
                    const v2f S = sxx + syy;
                    const v2f D = sxx - syy;
                    const v2f E = sxy + sxy;
                    const v2f disc = vfma2(D, D, vfma2(E, E, v2f{4e-10f, 4e-10f}));
                    const v2f qv = {__builtin_sqrtf(disc.x), __builtin_sqrtf(disc.y)};
                    const v2f lam = (S - qv) * 0.5f;
                    rv[2 * q]     = fmaxf(lam.x, 0.0f);
                    rv[2 * q + 1] = fmaxf(lam.y, 0.0f);
                }
                float* orowp = outb + (size_t)(s0 + rr - 2) * IMG_W + vb;
                __builtin_nontemporal_store(v4f{rv[0], rv[1], rv[2], rv[3]},
                                            (v4f*)orowp);
            }
        }
    }
}

__global__ __launch_bounds__(256, 3)
void shi_tomasi_kernel(const float* __restrict__ img, float* __restrict__ out) {
    const int cg    = threadIdx.x & 63;            // 64 col-groups x 4 cols
    const int strip = threadIdx.x >> 6;            // wave-uniform strip 0..3
    const int vb = blockIdx.x * 256 + cg * 4;
    if (vb >= IMG_W) return;                       // masked half of block x=7
    const int s0 = blockIdx.y * BROWS + strip * LSTRIP;
    const float* g = img + (size_t)blockIdx.z * (IMG_H * IMG_W);
    float* outb = out + (size_t)blockIdx.z * (IMG_H * IMG_W);

    if (blockIdx.x == 0 || blockIdx.x == gridDim.x - 1)
        st_body<true>(g, outb, vb, s0);
    else
        st_body<false>(g, outb, vb, s0);
}

extern "C" void kernel_launch(void* const* d_in, const int* in_sizes, int n_in,
                              void* d_out, int out_size, void* d_ws, size_t ws_size,
                              hipStream_t stream) {
    const float* img = (const float*)d_in[0];
    float* out = (float*)d_out;
    dim3 grid(8, IMG_H / BROWS, NBATCH);           // 8 x 30 x 8 = 1920 blocks
    shi_tomasi_kernel<<<grid, 256, 0, stream>>>(img, out);
}